// Round 1
// baseline (487.333 us; speedup 1.0000x reference)
//
#include <hip/hip_runtime.h>
#include <hip/hip_bf16.h>
#include <math.h>

typedef __bf16 bf16_t;
typedef __bf16 bf16x8 __attribute__((ext_vector_type(8)));
typedef float  f32x4  __attribute__((ext_vector_type(4)));

static constexpr int S_LEN = 4096;
static constexpr int D_DIM = 64;
static constexpr int H_NUM = 16;
static constexpr int BM    = 64;   // q rows per block
static constexpr int BT    = 32;   // kv cols per step
static constexpr float SCALE = 0.125f;                 // 1/sqrt(64)
static constexpr float LOG2E = 1.4426950408889634f;

// Flash attention fwd, causal. 4 waves/block, wave owns 16 q-rows.
// MFMA 16x16x32 bf16. C-layout: row = quad*4+reg, col = lane&15 (m89-verified).
// A-layout: A[m=lane&15][k=quad*8+j] (m120-verified). P goes C->A via LDS.
__global__ __launch_bounds__(256, 2)
void attn_fwd(const float* __restrict__ qg, const float* __restrict__ kg,
              const float* __restrict__ vg, float* __restrict__ og) {
  __shared__ bf16_t p_lds[4][16 * BT];   // per-wave private 16x32 bf16 = 1 KB each

  const int tid  = threadIdx.x;
  const int wave = tid >> 6;
  const int lane = tid & 63;
  const int col  = lane & 15;   // MFMA n / C-col
  const int quad = lane >> 4;   // 0..3

  const int h     = blockIdx.x >> 6;    // 64 q-tiles per head
  const int qt    = blockIdx.x & 63;
  const int qbase = qt * BM;
  const int qrow0 = qbase + wave * 16;  // wave's first q row
  const int myrow = qrow0 + quad * 4;   // C-layout rows myrow+reg

  const float* qh = qg + (size_t)h * S_LEN * D_DIM;
  const float* kh = kg + (size_t)h * D_DIM * S_LEN;   // k is [D][S] (pre-transposed)
  const float* vh = vg + (size_t)h * S_LEN * D_DIM;
  float*       oh = og + (size_t)h * S_LEN * D_DIM;

  // ---- Q fragments (A-operand): m = col, k-chunk d = half*32 + quad*8 + j ----
  bf16x8 qa[2];
  {
    const float* qp = qh + (size_t)(qrow0 + col) * D_DIM + quad * 8;
    #pragma unroll
    for (int half = 0; half < 2; ++half) {
      f32x4 lo = *(const f32x4*)(qp + half * 32);
      f32x4 hi = *(const f32x4*)(qp + half * 32 + 4);
      #pragma unroll
      for (int j = 0; j < 4; ++j) {
        qa[half][j]     = (bf16_t)lo[j];
        qa[half][j + 4] = (bf16_t)hi[j];
      }
    }
  }

  // ---- online-softmax state ----
  f32x4 acc[4];                    // O accumulator: 4 col-tiles of 16 over D=64
  #pragma unroll
  for (int nt = 0; nt < 4; ++nt) acc[nt] = (f32x4){0.f, 0.f, 0.f, 0.f};
  float m_i[4], l_i[4];
  #pragma unroll
  for (int r = 0; r < 4; ++r) { m_i[r] = -INFINITY; l_i[r] = 0.f; }

  const int nsteps = (qbase + BM) / BT;   // causal: only t < qbase+64

  for (int s = 0; s < nsteps; ++s) {
    const int t0 = s * BT;

    // ---- QK^T: two 16-col tiles, each 2 MFMAs over D=64 ----
    f32x4 sc[2];
    sc[0] = (f32x4){0.f, 0.f, 0.f, 0.f};
    sc[1] = (f32x4){0.f, 0.f, 0.f, 0.f};
    #pragma unroll
    for (int ct = 0; ct < 2; ++ct) {
      #pragma unroll
      for (int half = 0; half < 2; ++half) {
        // B-operand: B[k = quad*8+j][n = col] = kh[d*S + t0 + ct*16 + col]
        const float* kp = kh + (size_t)(half * 32 + quad * 8) * S_LEN + t0 + ct * 16 + col;
        bf16x8 kb;
        #pragma unroll
        for (int j = 0; j < 8; ++j) kb[j] = (bf16_t)kp[(size_t)j * S_LEN];
        sc[ct] = __builtin_amdgcn_mfma_f32_16x16x32_bf16(qa[half], kb, sc[ct], 0, 0, 0);
      }
    }

    // ---- scale, causal mask, online softmax ----
    #pragma unroll
    for (int r = 0; r < 4; ++r) {
      const int qr = myrow + r;
      float s0 = sc[0][r] * SCALE;
      float s1 = sc[1][r] * SCALE;
      if (t0 + col      > qr) s0 = -1e9f;
      if (t0 + 16 + col > qr) s1 = -1e9f;

      // row max across the 16 lanes of this quad
      float mx = fmaxf(s0, s1);
      mx = fmaxf(mx, __shfl_xor(mx, 1, 16));
      mx = fmaxf(mx, __shfl_xor(mx, 2, 16));
      mx = fmaxf(mx, __shfl_xor(mx, 4, 16));
      mx = fmaxf(mx, __shfl_xor(mx, 8, 16));

      const float m_new = fmaxf(m_i[r], mx);
      const float alpha = exp2f((m_i[r] - m_new) * LOG2E);
      const float p0 = exp2f((s0 - m_new) * LOG2E);
      const float p1 = exp2f((s1 - m_new) * LOG2E);

      float rs = p0 + p1;
      rs += __shfl_xor(rs, 1, 16);
      rs += __shfl_xor(rs, 2, 16);
      rs += __shfl_xor(rs, 4, 16);
      rs += __shfl_xor(rs, 8, 16);

      l_i[r] = l_i[r] * alpha + rs;
      m_i[r] = m_new;
      #pragma unroll
      for (int nt = 0; nt < 4; ++nt) acc[nt][r] *= alpha;

      // stash P (C-layout) into LDS as bf16
      const int rl = quad * 4 + r;   // local row 0..15
      p_lds[wave][rl * BT + col]      = (bf16_t)p0;
      p_lds[wave][rl * BT + col + 16] = (bf16_t)p1;
    }

    __syncthreads();   // intra-wave LDS write->read ordering (regions are wave-private)

    // ---- P: LDS -> A-operand fragment ----
    bf16x8 pa = *(const bf16x8*)&p_lds[wave][col * BT + quad * 8];

    // ---- PV: 4 col-tiles over D, K=32 over t ----
    #pragma unroll
    for (int nt = 0; nt < 4; ++nt) {
      // B-operand: B[k = quad*8+j][n = col] = vh[(t0+k)*D + nt*16 + col]
      const float* vp = vh + (size_t)(t0 + quad * 8) * D_DIM + nt * 16 + col;
      bf16x8 vb;
      #pragma unroll
      for (int j = 0; j < 8; ++j) vb[j] = (bf16_t)vp[(size_t)j * D_DIM];
      acc[nt] = __builtin_amdgcn_mfma_f32_16x16x32_bf16(pa, vb, acc[nt], 0, 0, 0);
    }

    __syncthreads();   // keep waves in step before next tile's LDS writes
  }

  // ---- epilogue: O / l ----
  #pragma unroll
  for (int r = 0; r < 4; ++r) {
    const int qr = myrow + r;
    const float inv_l = 1.0f / l_i[r];
    float* op = oh + (size_t)qr * D_DIM + col;
    #pragma unroll
    for (int nt = 0; nt < 4; ++nt) op[nt * 16] = acc[nt][r] * inv_l;
  }
}

extern "C" void kernel_launch(void* const* d_in, const int* in_sizes, int n_in,
                              void* d_out, int out_size, void* d_ws, size_t ws_size,
                              hipStream_t stream) {
  const float* q = (const float*)d_in[0];
  const float* k = (const float*)d_in[1];
  const float* v = (const float*)d_in[2];
  float* out = (float*)d_out;

  dim3 grid(H_NUM * (S_LEN / BM));   // 16 heads * 64 q-tiles = 1024 blocks
  dim3 block(256);
  attn_fwd<<<grid, block, 0, stream>>>(q, k, v, out);
}

// Round 2
// 277.583 us; speedup vs baseline: 1.7556x; 1.7556x over previous
//
#include <hip/hip_runtime.h>
#include <hip/hip_bf16.h>
#include <math.h>

typedef __bf16 bf16_t;
typedef __bf16 bf16x4 __attribute__((ext_vector_type(4)));
typedef __bf16 bf16x8 __attribute__((ext_vector_type(8)));
typedef float  f32x2  __attribute__((ext_vector_type(2)));
typedef float  f32x4  __attribute__((ext_vector_type(4)));

static constexpr int S_LEN = 4096;
static constexpr int D_DIM = 64;
static constexpr int H_NUM = 16;
static constexpr int BM    = 128;  // q rows per block: 4 waves x 2 tiles of 16 (tiles 64 apart)
static constexpr int BT    = 64;   // kv cols per step
static constexpr int SP    = 72;   // padded LDS row stride (bf16): 144 B -> conflict-free b128
static constexpr float QSCALE = 0.18033688011112042f;  // (1/sqrt(64)) * log2(e), folded into Q

// ---- DPP 16-lane row reductions (VALU-only, keeps softmax off the LDS pipe) ----
template<int CTRL>
__device__ __forceinline__ float dpp_mov(float x) {
  return __builtin_bit_cast(float,
      __builtin_amdgcn_update_dpp(0, __builtin_bit_cast(int, x), CTRL, 0xF, 0xF, true));
}
__device__ __forceinline__ float row_max16(float x) {
  x = fmaxf(x, dpp_mov<0xB1>(x));    // quad_perm(1,0,3,2)  xor1
  x = fmaxf(x, dpp_mov<0x4E>(x));    // quad_perm(2,3,0,1)  xor2
  x = fmaxf(x, dpp_mov<0x141>(x));   // row_half_mirror     (pairs quads)
  x = fmaxf(x, dpp_mov<0x140>(x));   // row_mirror          (pairs halves)
  return x;
}
__device__ __forceinline__ float row_sum16(float x) {
  x += dpp_mov<0xB1>(x);
  x += dpp_mov<0x4E>(x);
  x += dpp_mov<0x141>(x);
  x += dpp_mov<0x140>(x);
  return x;
}

// Flash attention fwd, causal. BM=128 q rows/block, BT=64 kv/step.
// MFMA 16x16x32 bf16. A[m=col][k=quad*8+j]; B[k=quad*8+j][n=col];
// C row=quad*4+reg, col=lane&15 (all verified by round-1 pass).
// K tile staged transposed: kT[t][d]; V staged transposed+permuted: vT[d][t'],
// t' = (t%16)*4 + t/16 so the P store is a single b64 per row.
__global__ __launch_bounds__(256, 2)
void attn_fwd(const float* __restrict__ qg, const float* __restrict__ kg,
              const float* __restrict__ vg, float* __restrict__ og) {
  __shared__ __align__(16) bf16_t kT[BT][SP];       // 9216 B
  __shared__ __align__(16) bf16_t vT[D_DIM][SP];    // 9216 B
  __shared__ __align__(16) bf16_t pT[4][32][SP];    // 18432 B (per-wave P, 2 tiles x 16 rows)

  const int tid  = threadIdx.x;
  const int wave = tid >> 6;
  const int lane = tid & 63;
  const int col  = lane & 15;
  const int quad = lane >> 4;

  // causal load balance: heavy q-tiles first, then light ones ascending
  const int h  = blockIdx.x & 15;
  const int jb = blockIdx.x >> 4;                  // 0..31
  const int qt = (jb < 16) ? (31 - jb) : (jb - 16);
  const int qbase = qt * BM;

  const float* qh = qg + (size_t)h * S_LEN * D_DIM;
  const float* kh = kg + (size_t)h * D_DIM * S_LEN;   // k is [D][S]
  const float* vh = vg + (size_t)h * S_LEN * D_DIM;
  float*       oh = og + (size_t)h * S_LEN * D_DIM;

  const int wr0 = qbase + wave * 16;   // wave's tile rt covers rows wr0 + rt*64 + [0,16)

  // ---- Q fragments (A-operand), pre-scaled by 1/sqrt(D)*log2e (exact-ish in bf16) ----
  bf16x8 qa[2][2];
  #pragma unroll
  for (int rt = 0; rt < 2; ++rt) {
    const float* qp = qh + (size_t)(wr0 + rt * 64 + col) * D_DIM + quad * 8;
    #pragma unroll
    for (int kk = 0; kk < 2; ++kk) {
      f32x4 lo = *(const f32x4*)(qp + kk * 32);
      f32x4 hi = *(const f32x4*)(qp + kk * 32 + 4);
      #pragma unroll
      for (int j = 0; j < 4; ++j) {
        qa[rt][kk][j]     = (bf16_t)(lo[j] * QSCALE);
        qa[rt][kk][j + 4] = (bf16_t)(hi[j] * QSCALE);
      }
    }
  }

  // ---- state ----
  f32x4 acc[2][4];
  #pragma unroll
  for (int rt = 0; rt < 2; ++rt)
    #pragma unroll
    for (int nt = 0; nt < 4; ++nt) acc[rt][nt] = (f32x4){0.f, 0.f, 0.f, 0.f};
  float m_i[2][4], l_i[2][4];
  #pragma unroll
  for (int rt = 0; rt < 2; ++rt)
    #pragma unroll
    for (int r = 0; r < 4; ++r) { m_i[rt][r] = -3.0e38f; l_i[rt][r] = 0.f; }

  const int nsteps = (qbase + BM) / BT;

  for (int s = 0; s < nsteps; ++s) {
    const int t0 = s * BT;

    // ---- stage K: kT[t][d] = K[d][t0+t], coalesced dwordx2, b128 LDS writes ----
    {
      const int tp = tid & 31, dg = tid >> 5;     // t = 2*tp, d octet = dg*8
      const float* kb = kh + (size_t)(dg * 8) * S_LEN + t0 + 2 * tp;
      f32x2 kv[8];
      #pragma unroll
      for (int u = 0; u < 8; ++u) kv[u] = *(const f32x2*)(kb + (size_t)u * S_LEN);
      bf16x8 r0, r1;
      #pragma unroll
      for (int u = 0; u < 8; ++u) { r0[u] = (bf16_t)kv[u][0]; r1[u] = (bf16_t)kv[u][1]; }
      *(bf16x8*)&kT[2 * tp][dg * 8]     = r0;
      *(bf16x8*)&kT[2 * tp + 1][dg * 8] = r1;
    }
    // ---- stage V: vT[d][t'] = V[t0+t(t')][d], t(t') = (t'&3)*16 + (t'>>2) ----
    {
      const int dp = tid & 31, tg = tid >> 5;     // d = 2*dp, t' octet = tg*8
      f32x2 vv[8];
      #pragma unroll
      for (int u = 0; u < 8; ++u) {
        const int tpr = tg * 8 + u;
        const int t   = ((tpr & 3) << 4) + (tpr >> 2);
        vv[u] = *(const f32x2*)(vh + (size_t)(t0 + t) * D_DIM + 2 * dp);
      }
      bf16x8 r0, r1;
      #pragma unroll
      for (int u = 0; u < 8; ++u) { r0[u] = (bf16_t)vv[u][0]; r1[u] = (bf16_t)vv[u][1]; }
      *(bf16x8*)&vT[2 * dp][tg * 8]     = r0;
      *(bf16x8*)&vT[2 * dp + 1][tg * 8] = r1;
    }

    __syncthreads();

    const bool act0 = (t0 <= wr0 + 15);   // rt=0 tile has any unmasked col (rt=1 always does)

    // ---- QK^T: K-frag read once, used by both row-tiles ----
    f32x4 sc[2][4];
    #pragma unroll
    for (int rt = 0; rt < 2; ++rt)
      #pragma unroll
      for (int ct = 0; ct < 4; ++ct) sc[rt][ct] = (f32x4){0.f, 0.f, 0.f, 0.f};
    if (act0) {
      #pragma unroll
      for (int ct = 0; ct < 4; ++ct)
        #pragma unroll
        for (int kk = 0; kk < 2; ++kk) {
          const bf16x8 kf = *(const bf16x8*)&kT[ct * 16 + col][kk * 32 + quad * 8];
          sc[0][ct] = __builtin_amdgcn_mfma_f32_16x16x32_bf16(qa[0][kk], kf, sc[0][ct], 0, 0, 0);
          sc[1][ct] = __builtin_amdgcn_mfma_f32_16x16x32_bf16(qa[1][kk], kf, sc[1][ct], 0, 0, 0);
        }
    } else {
      #pragma unroll
      for (int ct = 0; ct < 4; ++ct)
        #pragma unroll
        for (int kk = 0; kk < 2; ++kk) {
          const bf16x8 kf = *(const bf16x8*)&kT[ct * 16 + col][kk * 32 + quad * 8];
          sc[1][ct] = __builtin_amdgcn_mfma_f32_16x16x32_bf16(qa[1][kk], kf, sc[1][ct], 0, 0, 0);
        }
    }

    // ---- online softmax (base-2 domain; scale folded into Q) ----
    #pragma unroll
    for (int rt = 0; rt < 2; ++rt) {
      if (rt == 0 && !act0) continue;
      const int qrb = wr0 + rt * 64;
      const bool need_mask = (t0 + BT - 1 > qrb);
      #pragma unroll
      for (int r = 0; r < 4; ++r) {
        const int qr = qrb + quad * 4 + r;
        float s0 = sc[rt][0][r], s1 = sc[rt][1][r], s2 = sc[rt][2][r], s3 = sc[rt][3][r];
        if (need_mask) {
          if (t0 +      col > qr) s0 = -1e30f;
          if (t0 + 16 + col > qr) s1 = -1e30f;
          if (t0 + 32 + col > qr) s2 = -1e30f;
          if (t0 + 48 + col > qr) s3 = -1e30f;
        }
        const float mx   = row_max16(fmaxf(fmaxf(s0, s1), fmaxf(s2, s3)));
        const float mold = m_i[rt][r];
        const float mnew = fmaxf(mold, mx);
        const float alpha = exp2f(mold - mnew);
        const float p0 = exp2f(s0 - mnew);
        const float p1 = exp2f(s1 - mnew);
        const float p2 = exp2f(s2 - mnew);
        const float p3 = exp2f(s3 - mnew);
        const float rs = row_sum16((p0 + p1) + (p2 + p3));
        l_i[rt][r] = l_i[rt][r] * alpha + rs;
        m_i[rt][r] = mnew;
        #pragma unroll
        for (int nt = 0; nt < 4; ++nt) acc[rt][nt][r] *= alpha;
        // P store with t' = col*4 + ct permutation -> single b64
        bf16x4 pk = { (bf16_t)p0, (bf16_t)p1, (bf16_t)p2, (bf16_t)p3 };
        *(bf16x4*)&pT[wave][rt * 16 + quad * 4 + r][col * 4] = pk;
      }
    }

    __threadfence_block();   // same-wave P write -> read ordering (lgkmcnt drain)

    // ---- PV: V-frag read once, used by both row-tiles; P reused over 4 D-tiles ----
    #pragma unroll
    for (int kt = 0; kt < 2; ++kt) {
      const bf16x8 pa1 = *(const bf16x8*)&pT[wave][16 + col][kt * 32 + quad * 8];
      const bf16x8 pa0 = *(const bf16x8*)&pT[wave][col][kt * 32 + quad * 8];
      if (act0) {
        #pragma unroll
        for (int nt = 0; nt < 4; ++nt) {
          const bf16x8 vf = *(const bf16x8*)&vT[nt * 16 + col][kt * 32 + quad * 8];
          acc[0][nt] = __builtin_amdgcn_mfma_f32_16x16x32_bf16(pa0, vf, acc[0][nt], 0, 0, 0);
          acc[1][nt] = __builtin_amdgcn_mfma_f32_16x16x32_bf16(pa1, vf, acc[1][nt], 0, 0, 0);
        }
      } else {
        #pragma unroll
        for (int nt = 0; nt < 4; ++nt) {
          const bf16x8 vf = *(const bf16x8*)&vT[nt * 16 + col][kt * 32 + quad * 8];
          acc[1][nt] = __builtin_amdgcn_mfma_f32_16x16x32_bf16(pa1, vf, acc[1][nt], 0, 0, 0);
        }
      }
    }

    __syncthreads();   // all LDS reads done before next step's staging overwrites
  }

  // ---- epilogue ----
  #pragma unroll
  for (int rt = 0; rt < 2; ++rt)
    #pragma unroll
    for (int r = 0; r < 4; ++r) {
      const int qr = wr0 + rt * 64 + quad * 4 + r;
      const float inv_l = 1.0f / l_i[rt][r];
      float* op = oh + (size_t)qr * D_DIM + col;
      #pragma unroll
      for (int nt = 0; nt < 4; ++nt) op[nt * 16] = acc[rt][nt][r] * inv_l;
    }
}

extern "C" void kernel_launch(void* const* d_in, const int* in_sizes, int n_in,
                              void* d_out, int out_size, void* d_ws, size_t ws_size,
                              hipStream_t stream) {
  const float* q = (const float*)d_in[0];
  const float* k = (const float*)d_in[1];
  const float* v = (const float*)d_in[2];
  float* out = (float*)d_out;

  dim3 grid(H_NUM * (S_LEN / BM));   // 16 heads x 32 q-tiles = 512 blocks
  dim3 block(256);
  attn_fwd<<<grid, block, 0, stream>>>(q, k, v, out);
}

// Round 3
// 216.922 us; speedup vs baseline: 2.2466x; 1.2796x over previous
//
#include <hip/hip_runtime.h>
#include <hip/hip_bf16.h>
#include <math.h>

typedef __bf16 bf16_t;
typedef __bf16 bf16x4 __attribute__((ext_vector_type(4)));
typedef __bf16 bf16x8 __attribute__((ext_vector_type(8)));
typedef float  f32x2  __attribute__((ext_vector_type(2)));
typedef float  f32x4  __attribute__((ext_vector_type(4)));

static constexpr int S_LEN = 4096;
static constexpr int D_DIM = 64;
static constexpr int H_NUM = 16;
static constexpr int BM    = 128;  // q rows per block: 4 waves x 2 tiles of 16 (64 apart)
static constexpr int BT    = 64;   // kv cols per step
static constexpr int SP    = 72;   // padded LDS row stride (bf16): 144 B, 16B-aligned rows
static constexpr float QSCALE = 0.18033688011112042f;  // (1/sqrt(64)) * log2(e)

// S^T-formulation flash attention, causal.
// QK^T: Sᵀ[t][q] : A = Kᵀ (from kT LDS), B = Qᵀ (registers).
// PV:   Oᵀ[d][q] : A = Vᵀ (from vT LDS), B = Pᵀ (via wave-private pT LDS).
// MFMA 16x16x32 bf16: A[m=lane&15][k=quad*8+j]; B[k=quad*8+j][n=lane&15];
// C row(m)=quad*4+reg, col(n)=lane&15. In Sᵀ/Oᵀ the n-dim is the q-row, so
// softmax state (m,l,alpha) is ONE scalar per lane (replicated over quads).
// Double-buffered K/V staging + register prefetch -> single barrier per step.
__global__ __launch_bounds__(256, 2)
void attn_fwd(const float* __restrict__ qg, const float* __restrict__ kg,
              const float* __restrict__ vg, float* __restrict__ og) {
  __shared__ __align__(16) bf16_t kT[2][BT][SP];      // K^T tile: [t][d], 2 buffers
  __shared__ __align__(16) bf16_t vT[2][D_DIM][SP];   // V^T tile: [d][t], 2 buffers
  __shared__ __align__(16) bf16_t pT[4][32][SP];      // P^T per wave: [q_local][t]

  const int tid  = threadIdx.x;
  const int wave = tid >> 6;
  const int lane = tid & 63;
  const int col  = lane & 15;
  const int quad = lane >> 4;

  // causal load balance: heavy q-tiles first
  const int h  = blockIdx.x & 15;
  const int jb = blockIdx.x >> 4;                  // 0..31
  const int qt = (jb < 16) ? (31 - jb) : (jb - 16);
  const int qbase = qt * BM;

  const float* qh = qg + (size_t)h * S_LEN * D_DIM;
  const float* kh = kg + (size_t)h * D_DIM * S_LEN;   // k is [D][S]
  const float* vh = vg + (size_t)h * S_LEN * D_DIM;
  float*       oh = og + (size_t)h * S_LEN * D_DIM;

  const int wr0 = qbase + wave * 16;   // wave row-tile rt at wr0 + rt*64 + [0,16)

  // staging thread mapping
  const int tp = tid & 31, dg = tid >> 5;   // K: t=2*tp, d-octet=dg*8
  const int dp = tid & 31, tg = tid >> 5;   // V: d=2*dp, t-octet=tg*8

  // ---- Q^T B-fragments (registers, scaled) ----
  bf16x8 qb[2][2];
  #pragma unroll
  for (int rt = 0; rt < 2; ++rt) {
    const float* qp = qh + (size_t)(wr0 + rt * 64 + col) * D_DIM;
    #pragma unroll
    for (int kk = 0; kk < 2; ++kk) {
      f32x4 lo = *(const f32x4*)(qp + kk * 32 + quad * 8);
      f32x4 hi = *(const f32x4*)(qp + kk * 32 + quad * 8 + 4);
      #pragma unroll
      for (int j = 0; j < 4; ++j) {
        qb[rt][kk][j]     = (bf16_t)(lo[j] * QSCALE);
        qb[rt][kk][j + 4] = (bf16_t)(hi[j] * QSCALE);
      }
    }
  }

  // ---- state: O^T accumulators + per-lane scalar m,l per row-tile ----
  f32x4 acc[2][4];
  #pragma unroll
  for (int rt = 0; rt < 2; ++rt)
    #pragma unroll
    for (int nt = 0; nt < 4; ++nt) acc[rt][nt] = (f32x4){0.f, 0.f, 0.f, 0.f};
  float m_i[2] = {-1e30f, -1e30f}, l_i[2] = {0.f, 0.f};

  const int nsteps = (qbase + BM) / BT;

  // ---- prologue: stage step 0 into buffer 0 ----
  {
    const float* kb = kh + (size_t)(dg * 8) * S_LEN + 2 * tp;
    f32x2 kv[8];
    #pragma unroll
    for (int u = 0; u < 8; ++u) kv[u] = *(const f32x2*)(kb + (size_t)u * S_LEN);
    f32x2 vv[8];
    #pragma unroll
    for (int u = 0; u < 8; ++u) vv[u] = *(const f32x2*)(vh + (size_t)(tg * 8 + u) * D_DIM + 2 * dp);
    bf16x8 k0, k1, v0, v1;
    #pragma unroll
    for (int u = 0; u < 8; ++u) {
      k0[u] = (bf16_t)kv[u][0]; k1[u] = (bf16_t)kv[u][1];
      v0[u] = (bf16_t)vv[u][0]; v1[u] = (bf16_t)vv[u][1];
    }
    *(bf16x8*)&kT[0][2 * tp][dg * 8]     = k0;
    *(bf16x8*)&kT[0][2 * tp + 1][dg * 8] = k1;
    *(bf16x8*)&vT[0][2 * dp][tg * 8]     = v0;
    *(bf16x8*)&vT[0][2 * dp + 1][tg * 8] = v1;
  }
  __syncthreads();

  for (int s = 0; s < nsteps; ++s) {
    const int buf = s & 1;
    const int t0  = s * BT;
    const bool pf = (s + 1 < nsteps);

    // ---- prefetch next K/V tile into registers (latency hidden by compute) ----
    f32x2 kpre[8], vpre[8];
    if (pf) {
      const int t0n = t0 + BT;
      const float* kb = kh + (size_t)(dg * 8) * S_LEN + t0n + 2 * tp;
      #pragma unroll
      for (int u = 0; u < 8; ++u) kpre[u] = *(const f32x2*)(kb + (size_t)u * S_LEN);
      #pragma unroll
      for (int u = 0; u < 8; ++u)
        vpre[u] = *(const f32x2*)(vh + (size_t)(t0n + tg * 8 + u) * D_DIM + 2 * dp);
    }

    const bool act0 = (t0 <= wr0 + 15);   // rt=0 tile active (rt=1 always is)

    // ---- QK^T -> S^T ----
    f32x4 sc[2][4];
    #pragma unroll
    for (int rt = 0; rt < 2; ++rt)
      #pragma unroll
      for (int ct = 0; ct < 4; ++ct) sc[rt][ct] = (f32x4){0.f, 0.f, 0.f, 0.f};
    #pragma unroll
    for (int ct = 0; ct < 4; ++ct)
      #pragma unroll
      for (int kk = 0; kk < 2; ++kk) {
        const bf16x8 kf = *(const bf16x8*)&kT[buf][ct * 16 + col][kk * 32 + quad * 8];
        if (act0)
          sc[0][ct] = __builtin_amdgcn_mfma_f32_16x16x32_bf16(kf, qb[0][kk], sc[0][ct], 0, 0, 0);
        sc[1][ct] = __builtin_amdgcn_mfma_f32_16x16x32_bf16(kf, qb[1][kk], sc[1][ct], 0, 0, 0);
      }

    // ---- softmax (base-2; per-lane scalar state since n-dim = q-row) ----
    #pragma unroll
    for (int rt = 0; rt < 2; ++rt) {
      if (rt == 0 && !act0) continue;
      const int qrow = wr0 + rt * 64 + col;           // this lane's q row
      if (t0 + BT - 1 > wr0 + rt * 64) {              // tile needs masking
        #pragma unroll
        for (int ct = 0; ct < 4; ++ct)
          #pragma unroll
          for (int r = 0; r < 4; ++r)
            if (t0 + ct * 16 + quad * 4 + r > qrow) sc[rt][ct][r] = -1e30f;
      }
      float mx = sc[rt][0][0];
      #pragma unroll
      for (int ct = 0; ct < 4; ++ct)
        #pragma unroll
        for (int r = 0; r < 4; ++r) mx = fmaxf(mx, sc[rt][ct][r]);
      mx = fmaxf(mx, __shfl_xor(mx, 16));
      mx = fmaxf(mx, __shfl_xor(mx, 32));
      const float mold = m_i[rt];
      const float mnew = fmaxf(mold, mx);
      const float alpha = exp2f(mold - mnew);
      float rs = 0.f;
      #pragma unroll
      for (int ct = 0; ct < 4; ++ct) {
        bf16x4 pk;
        #pragma unroll
        for (int r = 0; r < 4; ++r) {
          const float p = exp2f(sc[rt][ct][r] - mnew);
          rs += p;
          pk[r] = (bf16_t)p;
        }
        *(bf16x4*)&pT[wave][rt * 16 + col][ct * 16 + quad * 4] = pk;
      }
      rs += __shfl_xor(rs, 16);
      rs += __shfl_xor(rs, 32);
      l_i[rt] = l_i[rt] * alpha + rs;
      m_i[rt] = mnew;
      #pragma unroll
      for (int nt = 0; nt < 4; ++nt) {
        acc[rt][nt][0] *= alpha; acc[rt][nt][1] *= alpha;
        acc[rt][nt][2] *= alpha; acc[rt][nt][3] *= alpha;
      }
    }

    __threadfence_block();   // wave-private pT write->read ordering

    // ---- PV -> O^T ----
    bf16x8 pb[2][2];
    #pragma unroll
    for (int kt = 0; kt < 2; ++kt) {
      pb[1][kt] = *(const bf16x8*)&pT[wave][16 + col][kt * 32 + quad * 8];
      if (act0) pb[0][kt] = *(const bf16x8*)&pT[wave][col][kt * 32 + quad * 8];
    }
    #pragma unroll
    for (int kt = 0; kt < 2; ++kt)
      #pragma unroll
      for (int nt = 0; nt < 4; ++nt) {
        const bf16x8 vf = *(const bf16x8*)&vT[buf][nt * 16 + col][kt * 32 + quad * 8];
        if (act0)
          acc[0][nt] = __builtin_amdgcn_mfma_f32_16x16x32_bf16(vf, pb[0][kt], acc[0][nt], 0, 0, 0);
        acc[1][nt] = __builtin_amdgcn_mfma_f32_16x16x32_bf16(vf, pb[1][kt], acc[1][nt], 0, 0, 0);
      }

    // ---- write prefetched tile to the other buffer ----
    if (pf) {
      bf16x8 k0, k1, v0, v1;
      #pragma unroll
      for (int u = 0; u < 8; ++u) {
        k0[u] = (bf16_t)kpre[u][0]; k1[u] = (bf16_t)kpre[u][1];
        v0[u] = (bf16_t)vpre[u][0]; v1[u] = (bf16_t)vpre[u][1];
      }
      *(bf16x8*)&kT[buf ^ 1][2 * tp][dg * 8]     = k0;
      *(bf16x8*)&kT[buf ^ 1][2 * tp + 1][dg * 8] = k1;
      *(bf16x8*)&vT[buf ^ 1][2 * dp][tg * 8]     = v0;
      *(bf16x8*)&vT[buf ^ 1][2 * dp + 1][tg * 8] = v1;
    }
    __syncthreads();   // the ONLY barrier per step
  }

  // ---- epilogue: O = O^T / l, contiguous f32x4 stores ----
  #pragma unroll
  for (int rt = 0; rt < 2; ++rt) {
    const float inv_l = 1.0f / l_i[rt];
    const int qr = wr0 + rt * 64 + col;
    float* op = oh + (size_t)qr * D_DIM + quad * 4;
    #pragma unroll
    for (int nt = 0; nt < 4; ++nt) {
      f32x4 o;
      o[0] = acc[rt][nt][0] * inv_l; o[1] = acc[rt][nt][1] * inv_l;
      o[2] = acc[rt][nt][2] * inv_l; o[3] = acc[rt][nt][3] * inv_l;
      *(f32x4*)(op + nt * 16) = o;
    }
  }
}

extern "C" void kernel_launch(void* const* d_in, const int* in_sizes, int n_in,
                              void* d_out, int out_size, void* d_ws, size_t ws_size,
                              hipStream_t stream) {
  const float* q = (const float*)d_in[0];
  const float* k = (const float*)d_in[1];
  const float* v = (const float*)d_in[2];
  float* out = (float*)d_out;

  dim3 grid(H_NUM * (S_LEN / BM));   // 512 blocks
  dim3 block(256);
  attn_fwd<<<grid, block, 0, stream>>>(q, k, v, out);
}